// Round 1
// baseline (358.478 us; speedup 1.0000x reference)
//
#include <hip/hip_runtime.h>

// MaxUnpooling2D: B=16, H=128, W=128, C=64, S=2 -> out (16,256,256,64) f32.
// Mask construction guarantees each pooled element scatters into its OWN 2x2
// window (disjoint windows, no duplicate indices), so the scatter-add is
// exactly equivalent to a gather: each output cell (b, 2h+py, 2w+px, c) equals
// updates[b,h,w,c] iff mask[b,h,w,c] == flat(2h+py, 2w+px, c), else 0.
//
// One thread per (b,h,w, c/4): float4/int4 loads, four predicated float4
// stores (the 2x2 window). Every output element is written exactly once ->
// no memset, no atomics, full-line coalesced writes.

__global__ __launch_bounds__(256) void MaxUnpooling2D_13589276524630_kernel(
        const float4* __restrict__ upd,   // (B,H,W,C) as float4 groups
        const int4*   __restrict__ msk,   // (B,H,W,C) as int4 groups
        float4*       __restrict__ out)   // (B,Ho,Wo,C) as float4 groups
{
    // total threads = 16*128*128*(64/4) = 4,194,304
    const int tid = blockIdx.x * blockDim.x + threadIdx.x;

    // Decode (b,h,w,c) — flat input element index is exactly tid*4, so these
    // are pure bit-slices.
    const int c = (tid & 15) << 2;       // channel base: 0,4,...,60
    const int w = (tid >> 4) & 127;
    const int h = (tid >> 11) & 127;
    const int b = tid >> 18;

    const float4 u = upd[tid];
    const int4   m = msk[tid];

    const int obase_b = b << 22;         // b * (256*256*64)
    const int y0 = 2 * h;
    const int x0 = 2 * w;

#pragma unroll
    for (int py = 0; py < 2; ++py) {
#pragma unroll
        for (int px = 0; px < 2; ++px) {
            // per-batch flat index of (y, x, c) over (Ho=256, Wo=256, C=64)
            const int fbase = (((y0 + py) << 8) + (x0 + px)) * 64 + c;
            float4 v;
            v.x = (m.x == fbase    ) ? u.x : 0.0f;
            v.y = (m.y == fbase + 1) ? u.y : 0.0f;
            v.z = (m.z == fbase + 2) ? u.z : 0.0f;
            v.w = (m.w == fbase + 3) ? u.w : 0.0f;
            out[(obase_b + fbase) >> 2] = v;
        }
    }
}

extern "C" void kernel_launch(void* const* d_in, const int* in_sizes, int n_in,
                              void* d_out, int out_size, void* d_ws, size_t ws_size,
                              hipStream_t stream) {
    const float4* upd = (const float4*)d_in[0];
    const int4*   msk = (const int4*)d_in[1];
    float4*       out = (float4*)d_out;

    const int n_threads = 16 * 128 * 128 * (64 / 4);   // 4,194,304
    const int block = 256;
    const int grid = n_threads / block;                // 16,384

    MaxUnpooling2D_13589276524630_kernel<<<grid, block, 0, stream>>>(upd, msk, out);
}

// Round 3
// 343.890 us; speedup vs baseline: 1.0424x; 1.0424x over previous
//
#include <hip/hip_runtime.h>

// MaxUnpooling2D: B=16, H=128, W=128, C=64, S=2 -> out (16,256,256,64) f32.
// Mask construction guarantees each pooled element scatters into its OWN 2x2
// window (disjoint windows), so scatter-add == gather: output cell
// (b, 2h+py, 2w+px, c) = updates[b,h,w,c] iff mask matches its flat index.
//
// One thread per (b,h,w, c/4): nontemporal 16B loads, four nontemporal
// predicated 16B stores (the 2x2 window). Every output element written
// exactly once -> no memset, no atomics, no L2 pollution from the 256 MiB
// streaming output (hence the nt hints: zero reuse).
//
// Native clang vectors (ext_vector_type) are required: the nontemporal
// builtins reject HIP_vector_type structs.

typedef float f32x4 __attribute__((ext_vector_type(4)));
typedef int   i32x4 __attribute__((ext_vector_type(4)));

__global__ __launch_bounds__(256) void MaxUnpooling2D_13589276524630_kernel(
        const f32x4* __restrict__ upd,   // (B,H,W,C) as 4-float groups
        const i32x4* __restrict__ msk,   // (B,H,W,C) as 4-int groups
        f32x4*       __restrict__ out)   // (B,Ho,Wo,C) as 4-float groups
{
    // total threads = 16*128*128*(64/4) = 4,194,304
    const int tid = blockIdx.x * blockDim.x + threadIdx.x;

    // Flat input element index is tid*4 -> pure bit-slices.
    const int c = (tid & 15) << 2;       // channel base: 0,4,...,60
    const int w = (tid >> 4) & 127;
    const int h = (tid >> 11) & 127;
    const int b = tid >> 18;

    const f32x4 u = __builtin_nontemporal_load(&upd[tid]);
    const i32x4 m = __builtin_nontemporal_load(&msk[tid]);

    const int obase_b = b << 22;         // b * (256*256*64)
    const int y0 = 2 * h;
    const int x0 = 2 * w;

    // Precompute the four flat bases so the compiler can cluster the stores.
    int   fb[4];
    f32x4 v[4];
#pragma unroll
    for (int py = 0; py < 2; ++py) {
#pragma unroll
        for (int px = 0; px < 2; ++px) {
            const int i = py * 2 + px;
            fb[i] = (((y0 + py) << 8) + (x0 + px)) * 64 + c;
            v[i].x = (m.x == fb[i]    ) ? u.x : 0.0f;
            v[i].y = (m.y == fb[i] + 1) ? u.y : 0.0f;
            v[i].z = (m.z == fb[i] + 2) ? u.z : 0.0f;
            v[i].w = (m.w == fb[i] + 3) ? u.w : 0.0f;
        }
    }
#pragma unroll
    for (int i = 0; i < 4; ++i)
        __builtin_nontemporal_store(v[i], &out[(obase_b + fb[i]) >> 2]);
}

extern "C" void kernel_launch(void* const* d_in, const int* in_sizes, int n_in,
                              void* d_out, int out_size, void* d_ws, size_t ws_size,
                              hipStream_t stream) {
    const f32x4* upd = (const f32x4*)d_in[0];
    const i32x4* msk = (const i32x4*)d_in[1];
    f32x4*       out = (f32x4*)d_out;

    const int n_threads = 16 * 128 * 128 * (64 / 4);   // 4,194,304
    const int block = 256;
    const int grid = n_threads / block;                // 16,384

    MaxUnpooling2D_13589276524630_kernel<<<grid, block, 0, stream>>>(upd, msk, out);
}

// Round 4
// 343.656 us; speedup vs baseline: 1.0431x; 1.0007x over previous
//
#include <hip/hip_runtime.h>

// MaxUnpooling2D: B=16, H=128, W=128, C=64, S=2 -> out (16,256,256,64) f32.
// Mask construction guarantees each pooled element scatters into its OWN 2x2
// window (disjoint windows), so scatter-add == gather: output cell
// (b, 2h+py, 2w+px, c) = updates[b,h,w,c] iff mask matches its flat index.
//
// V3: 4 input float4-groups per thread, all 8 nontemporal loads issued up
// front (4x deeper per-wave load queue for HBM latency hiding), then 16
// nontemporal predicated stores. Every output element written exactly once
// -> no memset, no atomics, no L2 pollution (nt: zero reuse).

typedef float f32x4 __attribute__((ext_vector_type(4)));
typedef int   i32x4 __attribute__((ext_vector_type(4)));

__global__ __launch_bounds__(256) void MaxUnpooling2D_13589276524630_kernel(
        const f32x4* __restrict__ upd,   // (B,H,W,C) as 4-float groups
        const i32x4* __restrict__ msk,   // (B,H,W,C) as 4-int groups
        f32x4*       __restrict__ out)   // (B,Ho,Wo,C) as 4-float groups
{
    // 4,194,304 float4-groups total; 4 per thread; 256 threads/block.
    const int t0 = blockIdx.x * (4 * 256) + threadIdx.x;

    f32x4 u[4];
    i32x4 m[4];
#pragma unroll
    for (int j = 0; j < 4; ++j) {
        u[j] = __builtin_nontemporal_load(&upd[t0 + j * 256]);
        m[j] = __builtin_nontemporal_load(&msk[t0 + j * 256]);
    }

#pragma unroll
    for (int j = 0; j < 4; ++j) {
        const int tid = t0 + j * 256;
        // Flat input element index is tid*4 -> pure bit-slices.
        const int c = (tid & 15) << 2;       // channel base: 0,4,...,60
        const int w = (tid >> 4) & 127;
        const int h = (tid >> 11) & 127;
        const int b = tid >> 18;

        const int obase_b = b << 22;         // b * (256*256*64)
        const int y0 = 2 * h;
        const int x0 = 2 * w;

        int   fb[4];
        f32x4 v[4];
#pragma unroll
        for (int py = 0; py < 2; ++py) {
#pragma unroll
            for (int px = 0; px < 2; ++px) {
                const int i = py * 2 + px;
                fb[i] = (((y0 + py) << 8) + (x0 + px)) * 64 + c;
                v[i].x = (m[j].x == fb[i]    ) ? u[j].x : 0.0f;
                v[i].y = (m[j].y == fb[i] + 1) ? u[j].y : 0.0f;
                v[i].z = (m[j].z == fb[i] + 2) ? u[j].z : 0.0f;
                v[i].w = (m[j].w == fb[i] + 3) ? u[j].w : 0.0f;
            }
        }
#pragma unroll
        for (int i = 0; i < 4; ++i)
            __builtin_nontemporal_store(v[i], &out[(obase_b + fb[i]) >> 2]);
    }
}

extern "C" void kernel_launch(void* const* d_in, const int* in_sizes, int n_in,
                              void* d_out, int out_size, void* d_ws, size_t ws_size,
                              hipStream_t stream) {
    const f32x4* upd = (const f32x4*)d_in[0];
    const i32x4* msk = (const i32x4*)d_in[1];
    f32x4*       out = (f32x4*)d_out;

    const int n_groups = 16 * 128 * 128 * (64 / 4);    // 4,194,304 float4 groups
    const int block = 256;
    const int grid = n_groups / (block * 4);           // 4,096 blocks

    MaxUnpooling2D_13589276524630_kernel<<<grid, block, 0, stream>>>(upd, msk, out);
}